// Round 1
// baseline (115.672 us; speedup 1.0000x reference)
//
#include <hip/hip_runtime.h>
#include <hip/hip_bf16.h>

// Problem: N=64, K=512, D=256. Reference reduces to out = relu(x @ W^T + b):
// softmax over j sums to 1 and einsum 'nkj,nkd->nkd' multiplies h by that sum.
// So this is a [32768,256]x[256,256]^T GEMM + bias + ReLU, memory-bound
// (67 MB traffic, 4.3 GFLOP).

#define DD 256          // feature dim
#define M_TOTAL 32768   // N*K rows

typedef short bf16x8 __attribute__((ext_vector_type(8)));
typedef float floatx16 __attribute__((ext_vector_type(16)));

// ---- fp32 -> bf16 RNE (bit trick, no header dependence) ----
__device__ inline unsigned short f2bf(float f) {
    union { float f; unsigned u; } x; x.f = f;
    unsigned u = x.u;
    return (unsigned short)((u + 0x7FFFu + ((u >> 16) & 1u)) >> 16);
}

// Cast W [256x256] fp32 -> bf16 into workspace. 64 blocks x 256 threads x 4 elems.
__global__ void cast_w_kernel(const float* __restrict__ W,
                              unsigned short* __restrict__ Wb) {
    int i = (blockIdx.x * 256 + threadIdx.x) * 4;
    float4 v = *(const float4*)(W + i);
    union { ushort4 s; unsigned u[2]; } o;
    o.s.x = f2bf(v.x);
    o.s.y = f2bf(v.y);
    o.s.z = f2bf(v.z);
    o.s.w = f2bf(v.w);
    *(ushort4*)(Wb + i) = o.s;
}

// Pack 8 fp32 -> 8 bf16 using packed cvt (v_cvt_pk_bf16_f32).
__device__ inline bf16x8 pack8(float4 p0, float4 p1) {
    __hip_bfloat162 q0 = __float22bfloat162_rn(make_float2(p0.x, p0.y));
    __hip_bfloat162 q1 = __float22bfloat162_rn(make_float2(p0.z, p0.w));
    __hip_bfloat162 q2 = __float22bfloat162_rn(make_float2(p1.x, p1.y));
    __hip_bfloat162 q3 = __float22bfloat162_rn(make_float2(p1.z, p1.w));
    union { bf16x8 v; unsigned u[4]; } r;
    union { __hip_bfloat162 h; unsigned u; } c;
    c.h = q0; r.u[0] = c.u;
    c.h = q1; r.u[1] = c.u;
    c.h = q2; r.u[2] = c.u;
    c.h = q3; r.u[3] = c.u;
    return r.v;
}

// Main GEMM: out[m,e] = relu(sum_d x[m,d]*W[e,d] + b[e]).
// Block = 8 waves (512 thr) = 2 m-waves x 4 e-waves. Wave = 32 m-rows x 64 e-cols.
// B fragments register-resident (whole 64x256 W-slice, 32 short8 = 128 VGPR).
// No LDS, no __syncthreads.
__global__ void __launch_bounds__(512, 2)
fcgat_gemm(const float* __restrict__ x, const unsigned short* __restrict__ Wb,
           const float* __restrict__ Wbias, float* __restrict__ out) {
    const int lane = threadIdx.x & 63;
    const int wave = threadIdx.x >> 6;   // 0..7
    const int ln   = lane & 31;          // m-row / e-col within tile
    const int lh   = lane >> 5;          // k-half selector (0/1)
    const int mw   = wave >> 2;          // 0..1
    const int ew   = wave & 3;           // 0..3
    const int m0   = blockIdx.x * 64 + mw * 32;
    const int e0   = ew * 64;

    // ---- load B fragments: Bf[t][s] = W[e0+t*32+ln][s*16 + lh*8 .. +8] ----
    bf16x8 Bf[2][16];
    const unsigned short* wbase = Wb + (e0 + ln) * DD + lh * 8;
#pragma unroll
    for (int t = 0; t < 2; ++t) {
        const unsigned short* wt = wbase + t * 32 * DD;
#pragma unroll
        for (int s = 0; s < 16; ++s) {
            Bf[t][s] = *(const bf16x8*)(wt + s * 16);
        }
    }

    floatx16 acc0 = {0.f};
    floatx16 acc1 = {0.f};
#pragma unroll
    for (int i = 0; i < 16; ++i) { acc0[i] = 0.f; acc1[i] = 0.f; }

    const float* xbase = x + (m0 + ln) * DD + lh * 8;
#pragma unroll
    for (int s = 0; s < 16; ++s) {
        float4 p0 = *(const float4*)(xbase + s * 16);
        float4 p1 = *(const float4*)(xbase + s * 16 + 4);
        bf16x8 a = pack8(p0, p1);
        acc0 = __builtin_amdgcn_mfma_f32_32x32x16_bf16(a, Bf[0][s], acc0, 0, 0, 0);
        acc1 = __builtin_amdgcn_mfma_f32_32x32x16_bf16(a, Bf[1][s], acc1, 0, 0, 0);
    }

    // ---- epilogue: bias + relu, fp32 store ----
    // C/D layout (measured): col = lane&31, row = (reg&3) + 8*(reg>>2) + 4*(lane>>5)
    const float b0 = Wbias[e0 + ln];
    const float b1 = Wbias[e0 + 32 + ln];
#pragma unroll
    for (int r = 0; r < 16; ++r) {
        const int m = m0 + (r & 3) + 8 * (r >> 2) + 4 * lh;
        float v0 = acc0[r] + b0;
        float v1 = acc1[r] + b1;
        v0 = v0 > 0.f ? v0 : 0.f;
        v1 = v1 > 0.f ? v1 : 0.f;
        out[m * DD + e0 + ln]      = v0;
        out[m * DD + e0 + 32 + ln] = v1;
    }
}

extern "C" void kernel_launch(void* const* d_in, const int* in_sizes, int n_in,
                              void* d_out, int out_size, void* d_ws, size_t ws_size,
                              hipStream_t stream) {
    const float* x    = (const float*)d_in[0];  // [64,512,256]
    const float* W_w  = (const float*)d_in[1];  // [256,256]
    const float* W_b  = (const float*)d_in[2];  // [256]
    // d_in[3] = att_w, d_in[4] = att_b — provably unused (softmax sums to 1)
    float* out = (float*)d_out;                 // [64,512,256] fp32
    unsigned short* Wb = (unsigned short*)d_ws; // 128 KB bf16 scratch

    cast_w_kernel<<<64, 256, 0, stream>>>(W_w, Wb);
    fcgat_gemm<<<M_TOTAL / 64, 512, 0, stream>>>(x, Wb, W_b, out);
}

// Round 2
// 108.382 us; speedup vs baseline: 1.0673x; 1.0673x over previous
//
#include <hip/hip_runtime.h>
#include <hip/hip_bf16.h>

// Problem: N=64, K=512, D=256. Reference reduces to out = relu(x @ W^T + b):
// softmax over j sums to 1 and einsum 'nkj,nkd->nkd' multiplies h by that sum.
// [32768,256] x [256,256]^T GEMM + bias + ReLU. Memory-bound: 67 MB traffic.
//
// R1 post-mortem: register-resident B forced compiler to AGPR-ize Bf (VGPR=36),
// serializing the A-stream -> latency-bound 42us @ 1.2 TB/s. R2: B via LDS,
// explicit 4-deep A prefetch in VGPRs.

#define DD 256          // feature dim
#define M_TOTAL 32768   // N*K rows
#define LW_STRIDE 264   // 256 + 8 shorts pad: keeps rows 16B-aligned (528 B)

typedef short bf16x8 __attribute__((ext_vector_type(8)));
typedef float floatx16 __attribute__((ext_vector_type(16)));

// ---- fp32 -> bf16 RNE ----
__device__ inline unsigned short f2bf(float f) {
    union { float f; unsigned u; } x; x.f = f;
    unsigned u = x.u;
    return (unsigned short)((u + 0x7FFFu + ((u >> 16) & 1u)) >> 16);
}

// Cast W [256x256] fp32 -> bf16 into workspace (e-major, same layout as W).
__global__ void cast_w_kernel(const float* __restrict__ W,
                              unsigned short* __restrict__ Wb) {
    int i = (blockIdx.x * 256 + threadIdx.x) * 4;
    float4 v = *(const float4*)(W + i);
    ushort4 o;
    o.x = f2bf(v.x); o.y = f2bf(v.y); o.z = f2bf(v.z); o.w = f2bf(v.w);
    *(ushort4*)(Wb + i) = o;
}

// Pack 8 fp32 -> 8 bf16 (packed cvt).
__device__ inline bf16x8 pack8(float4 p0, float4 p1) {
    __hip_bfloat162 q0 = __float22bfloat162_rn(make_float2(p0.x, p0.y));
    __hip_bfloat162 q1 = __float22bfloat162_rn(make_float2(p0.z, p0.w));
    __hip_bfloat162 q2 = __float22bfloat162_rn(make_float2(p1.x, p1.y));
    __hip_bfloat162 q3 = __float22bfloat162_rn(make_float2(p1.z, p1.w));
    union { bf16x8 v; unsigned u[4]; } r;
    union { __hip_bfloat162 h; unsigned u; } c;
    c.h = q0; r.u[0] = c.u;
    c.h = q1; r.u[1] = c.u;
    c.h = q2; r.u[2] = c.u;
    c.h = q3; r.u[3] = c.u;
    return r.v;
}

// Block = 4 waves x (32m x 64e), all waves share e-slice [e0, e0+64).
// Grid = 256 m-blocks x 4 e-blocks = 1024 blocks (4/CU, LDS-limited).
// W e-slice staged once in LDS (bf16, padded). A streamed with 4-deep prefetch.
__global__ void __launch_bounds__(256, 4)
fcgat_gemm(const float* __restrict__ x, const unsigned short* __restrict__ Wb,
           const float* __restrict__ Wbias, float* __restrict__ out) {
    __shared__ __align__(16) unsigned short lw[64 * LW_STRIDE];  // 33 KB

    const int tid  = threadIdx.x;
    const int lane = tid & 63;
    const int wave = tid >> 6;          // 0..3 -> m sub-tile
    const int ln   = lane & 31;         // m-row / e-col within 32x32 tile
    const int lh   = lane >> 5;         // k-half selector (0/1)
    const int mblk = blockIdx.x >> 2;
    const int e0   = (blockIdx.x & 3) * 64;
    const int m0   = mblk * 128 + wave * 32;

    // ---- stage W[e0:e0+64, :] bf16 -> LDS (padded rows) ----
    {
        const int r = tid >> 2;         // 0..63
        const int q = tid & 3;          // 0..3 -> 64-col quarter
        const unsigned short* src = Wb + (e0 + r) * DD + q * 64;
        unsigned short* dst = lw + r * LW_STRIDE + q * 64;
#pragma unroll
        for (int i = 0; i < 8; ++i) {
            *(bf16x8*)(dst + i * 8) = *(const bf16x8*)(src + i * 8);
        }
    }
    __syncthreads();

    floatx16 acc0, acc1;
#pragma unroll
    for (int i = 0; i < 16; ++i) { acc0[i] = 0.f; acc1[i] = 0.f; }

    const float* xb = x + (m0 + ln) * DD + lh * 8;
    const unsigned short* lb0 = lw + ln * LW_STRIDE + lh * 8;
    const unsigned short* lb1 = lb0 + 32 * LW_STRIDE;

    // ---- 4-deep rolling A prefetch ----
    float4 buf[4][2];
#pragma unroll
    for (int s = 0; s < 4; ++s) {
        buf[s][0] = *(const float4*)(xb + s * 16);
        buf[s][1] = *(const float4*)(xb + s * 16 + 4);
    }

#pragma unroll
    for (int s = 0; s < 16; ++s) {
        bf16x8 a  = pack8(buf[s & 3][0], buf[s & 3][1]);
        bf16x8 B0 = *(const bf16x8*)(lb0 + s * 16);
        bf16x8 B1 = *(const bf16x8*)(lb1 + s * 16);
        if (s + 4 < 16) {
            buf[s & 3][0] = *(const float4*)(xb + (s + 4) * 16);
            buf[s & 3][1] = *(const float4*)(xb + (s + 4) * 16 + 4);
        }
        acc0 = __builtin_amdgcn_mfma_f32_32x32x16_bf16(a, B0, acc0, 0, 0, 0);
        acc1 = __builtin_amdgcn_mfma_f32_32x32x16_bf16(a, B1, acc1, 0, 0, 0);
    }

    // ---- epilogue: bias + relu, fp32 store ----
    // C/D layout: col = lane&31, row = (reg&3) + 8*(reg>>2) + 4*(lane>>5)
    const float b0 = Wbias[e0 + ln];
    const float b1 = Wbias[e0 + 32 + ln];
#pragma unroll
    for (int r = 0; r < 16; ++r) {
        const int m = m0 + (r & 3) + 8 * (r >> 2) + 4 * lh;
        float v0 = acc0[r] + b0;
        float v1 = acc1[r] + b1;
        v0 = v0 > 0.f ? v0 : 0.f;
        v1 = v1 > 0.f ? v1 : 0.f;
        out[m * DD + e0 + ln]      = v0;
        out[m * DD + e0 + 32 + ln] = v1;
    }
}

extern "C" void kernel_launch(void* const* d_in, const int* in_sizes, int n_in,
                              void* d_out, int out_size, void* d_ws, size_t ws_size,
                              hipStream_t stream) {
    const float* x    = (const float*)d_in[0];  // [64,512,256]
    const float* W_w  = (const float*)d_in[1];  // [256,256]
    const float* W_b  = (const float*)d_in[2];  // [256]
    // d_in[3] = att_w, d_in[4] = att_b — provably unused (softmax sums to 1)
    float* out = (float*)d_out;                 // [64,512,256] fp32
    unsigned short* Wb = (unsigned short*)d_ws; // 128 KB bf16 scratch

    cast_w_kernel<<<64, 256, 0, stream>>>(W_w, Wb);
    fcgat_gemm<<<M_TOTAL / 128 * 4, 256, 0, stream>>>(x, Wb, W_b, out);
}

// Round 3
// 108.027 us; speedup vs baseline: 1.0708x; 1.0033x over previous
//
#include <hip/hip_runtime.h>
#include <hip/hip_bf16.h>

// Problem: N=64, K=512, D=256. Reference reduces to out = relu(x @ W^T + b):
// softmax over j sums to 1 and einsum 'nkj,nkd->nkd' multiplies h by that sum.
// [32768,256] x [256,256]^T GEMM + bias + ReLU. Memory-bound (~50-67 MB HBM).
//
// R1: register-resident B -> AGPR-ized, latency-bound 42us @ 1.2 TB/s.
// R2: LDS-staged W slice + 4-deep prefetch -> gemm <41us (fell out of top-5).
// R3: 8-deep prefetch (16 loads in flight, issued before staging so they
//     drain during the staging barrier), W cast fused into staging (cast
//     kernel dispatch eliminated), nontemporal out stores.

#define DD 256          // feature dim
#define M_TOTAL 32768   // N*K rows
#define LW_STRIDE 264   // 256 + 8 shorts pad: rows stay 16B-aligned (528 B)

typedef short bf16x8 __attribute__((ext_vector_type(8)));
typedef float floatx16 __attribute__((ext_vector_type(16)));

// Pack 8 fp32 -> 8 bf16 (packed cvt, RNE).
__device__ inline bf16x8 pack8(float4 p0, float4 p1) {
    __hip_bfloat162 q0 = __float22bfloat162_rn(make_float2(p0.x, p0.y));
    __hip_bfloat162 q1 = __float22bfloat162_rn(make_float2(p0.z, p0.w));
    __hip_bfloat162 q2 = __float22bfloat162_rn(make_float2(p1.x, p1.y));
    __hip_bfloat162 q3 = __float22bfloat162_rn(make_float2(p1.z, p1.w));
    union { bf16x8 v; unsigned u[4]; } r;
    union { __hip_bfloat162 h; unsigned u; } c;
    c.h = q0; r.u[0] = c.u;
    c.h = q1; r.u[1] = c.u;
    c.h = q2; r.u[2] = c.u;
    c.h = q3; r.u[3] = c.u;
    return r.v;
}

// Block = 4 waves x (32m x 64e), all waves share e-slice [e0, e0+64).
// Grid = 256 m-blocks x 4 e-blocks = 1024 blocks (4/CU, LDS 33 KB).
// W e-slice read fp32 -> cvt bf16 -> LDS (padded rows), fused (no cast kernel).
// A streamed with 8-deep rolling prefetch issued BEFORE staging.
__global__ void __launch_bounds__(256, 4)
fcgat_gemm(const float* __restrict__ x, const float* __restrict__ W,
           const float* __restrict__ Wbias, float* __restrict__ out) {
    __shared__ __align__(16) unsigned short lw[64 * LW_STRIDE];  // 33 KB

    const int tid  = threadIdx.x;
    const int lane = tid & 63;
    const int wave = tid >> 6;          // 0..3 -> m sub-tile
    const int ln   = lane & 31;         // m-row / e-col within 32x32 tile
    const int lh   = lane >> 5;         // k-half selector (0/1)
    const int mblk = blockIdx.x >> 2;
    const int e0   = (blockIdx.x & 3) * 64;
    const int m0   = mblk * 128 + wave * 32;

    const float* xb = x + (m0 + ln) * DD + lh * 8;

    // ---- issue 8-deep A prefetch FIRST (drains during staging barrier) ----
    float4 buf[8][2];
#pragma unroll
    for (int s = 0; s < 8; ++s) {
        buf[s][0] = *(const float4*)(xb + s * 16);
        buf[s][1] = *(const float4*)(xb + s * 16 + 4);
    }

    // ---- stage W[e0:e0+64, :] fp32 -> bf16 -> LDS (padded rows) ----
    {
        const int r = tid >> 2;         // 0..63
        const int q = tid & 3;          // 0..3 -> 64-col quarter
        const float* src = W + (e0 + r) * DD + q * 64;
        unsigned short* dst = lw + r * LW_STRIDE + q * 64;
#pragma unroll
        for (int i = 0; i < 8; ++i) {
            float4 a0 = *(const float4*)(src + i * 8);
            float4 a1 = *(const float4*)(src + i * 8 + 4);
            *(bf16x8*)(dst + i * 8) = pack8(a0, a1);
        }
    }
    __syncthreads();

    floatx16 acc0, acc1;
#pragma unroll
    for (int i = 0; i < 16; ++i) { acc0[i] = 0.f; acc1[i] = 0.f; }

    const unsigned short* lb0 = lw + ln * LW_STRIDE + lh * 8;
    const unsigned short* lb1 = lb0 + 32 * LW_STRIDE;

#pragma unroll
    for (int s = 0; s < 16; ++s) {
        bf16x8 a  = pack8(buf[s & 7][0], buf[s & 7][1]);
        bf16x8 B0 = *(const bf16x8*)(lb0 + s * 16);
        bf16x8 B1 = *(const bf16x8*)(lb1 + s * 16);
        if (s + 8 < 16) {
            buf[s & 7][0] = *(const float4*)(xb + (s + 8) * 16);
            buf[s & 7][1] = *(const float4*)(xb + (s + 8) * 16 + 4);
        }
        acc0 = __builtin_amdgcn_mfma_f32_32x32x16_bf16(a, B0, acc0, 0, 0, 0);
        acc1 = __builtin_amdgcn_mfma_f32_32x32x16_bf16(a, B1, acc1, 0, 0, 0);
    }

    // ---- epilogue: bias + relu, fp32 nontemporal store ----
    // C/D layout: col = lane&31, row = (reg&3) + 8*(reg>>2) + 4*(lane>>5)
    const float b0 = Wbias[e0 + ln];
    const float b1 = Wbias[e0 + 32 + ln];
    float* ob = out + e0 + ln;
#pragma unroll
    for (int r = 0; r < 16; ++r) {
        const int m = m0 + (r & 3) + 8 * (r >> 2) + 4 * lh;
        float v0 = acc0[r] + b0;
        float v1 = acc1[r] + b1;
        v0 = v0 > 0.f ? v0 : 0.f;
        v1 = v1 > 0.f ? v1 : 0.f;
        __builtin_nontemporal_store(v0, ob + m * DD);
        __builtin_nontemporal_store(v1, ob + m * DD + 32);
    }
}

extern "C" void kernel_launch(void* const* d_in, const int* in_sizes, int n_in,
                              void* d_out, int out_size, void* d_ws, size_t ws_size,
                              hipStream_t stream) {
    const float* x    = (const float*)d_in[0];  // [64,512,256]
    const float* W_w  = (const float*)d_in[1];  // [256,256]
    const float* W_b  = (const float*)d_in[2];  // [256]
    // d_in[3] = att_w, d_in[4] = att_b — provably unused (softmax sums to 1)
    float* out = (float*)d_out;                 // [64,512,256] fp32

    fcgat_gemm<<<M_TOTAL / 128 * 4, 256, 0, stream>>>(x, W_w, W_b, out);
}

// Round 4
// 102.088 us; speedup vs baseline: 1.1331x; 1.0582x over previous
//
#include <hip/hip_runtime.h>
#include <hip/hip_bf16.h>

// Problem: N=64, K=512, D=256. Reference reduces to out = relu(x @ W^T + b):
// softmax over j sums to 1 and einsum 'nkj,nkd->nkd' multiplies h by that sum.
// [32768,256] x [256,256]^T GEMM + bias + ReLU. Memory-bound (~67 MB HBM).
//
// R1: register-resident B -> AGPR-ized, latency-bound 42us @ 1.2 TB/s.
// R2/R3: LDS W + deep A-prefetch -> ~35us, prefetch depth neutral.
// R4 theory: loads were ADDRESS-DIVERGENT (lane stride 1024 B -> 64 line
// transactions per inst, 8x request amplification). Fix: stage x AND W via
// lane-contiguous fp32 loads -> bf16 -> LDS; MFMA frags via ds_read_b128.

#define DD 256          // feature dim
#define M_TOTAL 32768   // N*K rows
#define LWS 264         // LDS row stride in shorts (528 B, 16B-aligned)

typedef short bf16x8 __attribute__((ext_vector_type(8)));
typedef float floatx16 __attribute__((ext_vector_type(16)));

// Pack 8 fp32 -> 8 bf16 (packed cvt, RNE).
__device__ inline bf16x8 pack8(float4 p0, float4 p1) {
    __hip_bfloat162 q0 = __float22bfloat162_rn(make_float2(p0.x, p0.y));
    __hip_bfloat162 q1 = __float22bfloat162_rn(make_float2(p0.z, p0.w));
    __hip_bfloat162 q2 = __float22bfloat162_rn(make_float2(p1.x, p1.y));
    __hip_bfloat162 q3 = __float22bfloat162_rn(make_float2(p1.z, p1.w));
    union { bf16x8 v; unsigned u[4]; } r;
    union { __hip_bfloat162 h; unsigned u; } c;
    c.h = q0; r.u[0] = c.u;
    c.h = q1; r.u[1] = c.u;
    c.h = q2; r.u[2] = c.u;
    c.h = q3; r.u[3] = c.u;
    return r.v;
}

// Block = 256 thr = 4 waves (2m x 2e), tile 64m x 64e, wave tile 32x32.
// Grid = 512 m-blocks x 4 e-blocks = 2048 blocks, 2 blocks/CU (66 KB LDS).
// Staging: thread t -> row t>>5, col (t&31)*8 floats: lanes 0-31 cover one
// contiguous 1 KB row segment -> fully coalesced 128 B lines.
__global__ void __launch_bounds__(256, 2)
fcgat_gemm(const float* __restrict__ x, const float* __restrict__ W,
           const float* __restrict__ Wbias, float* __restrict__ out) {
    __shared__ __align__(16) unsigned short lx[64 * LWS];  // 33 KB
    __shared__ __align__(16) unsigned short lw[64 * LWS];  // 33 KB

    const int tid = threadIdx.x;
    const int bm  = blockIdx.x >> 2;
    const int e0  = (blockIdx.x & 3) * 64;
    const int m0  = bm * 64;

    // ---- coalesced staging: x[m0:m0+64,:] and W[e0:e0+64,:] fp32->bf16->LDS
    {
        const int sr = tid >> 5;          // 0..7 base row
        const int sc = (tid & 31) * 8;    // float col offset
        const float* xs = x + (m0 + sr) * DD + sc;
        const float* ws = W + (e0 + sr) * DD + sc;
        unsigned short* dx = lx + sr * LWS + sc;
        unsigned short* dw = lw + sr * LWS + sc;
#pragma unroll
        for (int i = 0; i < 8; ++i) {
            float4 a0 = *(const float4*)(xs + i * 8 * DD);
            float4 a1 = *(const float4*)(xs + i * 8 * DD + 4);
            float4 b0 = *(const float4*)(ws + i * 8 * DD);
            float4 b1 = *(const float4*)(ws + i * 8 * DD + 4);
            *(bf16x8*)(dx + i * 8 * LWS) = pack8(a0, a1);
            *(bf16x8*)(dw + i * 8 * LWS) = pack8(b0, b1);
        }
    }
    __syncthreads();

    const int lane = tid & 63;
    const int wave = tid >> 6;        // 0..3
    const int mw   = wave >> 1;       // 0..1 m sub-tile
    const int ew   = wave & 1;        // 0..1 e sub-tile
    const int ln   = lane & 31;
    const int lh   = lane >> 5;       // k-half (0/1)

    const unsigned short* ax = lx + (mw * 32 + ln) * LWS + lh * 8;
    const unsigned short* bw = lw + (ew * 32 + ln) * LWS + lh * 8;

    floatx16 acc;
#pragma unroll
    for (int i = 0; i < 16; ++i) acc[i] = 0.f;

#pragma unroll
    for (int s = 0; s < 16; ++s) {
        bf16x8 af = *(const bf16x8*)(ax + s * 16);
        bf16x8 bf = *(const bf16x8*)(bw + s * 16);
        acc = __builtin_amdgcn_mfma_f32_32x32x16_bf16(af, bf, acc, 0, 0, 0);
    }

    // ---- epilogue: bias + relu, fp32 nontemporal store ----
    // C/D layout: col = lane&31, row = (reg&3) + 8*(reg>>2) + 4*(lane>>5)
    const float bias = Wbias[e0 + ew * 32 + ln];
    float* ob = out + e0 + ew * 32 + ln;
#pragma unroll
    for (int r = 0; r < 16; ++r) {
        const int m = m0 + mw * 32 + (r & 3) + 8 * (r >> 2) + 4 * lh;
        float v = acc[r] + bias;
        v = v > 0.f ? v : 0.f;
        __builtin_nontemporal_store(v, ob + m * DD);
    }
}

extern "C" void kernel_launch(void* const* d_in, const int* in_sizes, int n_in,
                              void* d_out, int out_size, void* d_ws, size_t ws_size,
                              hipStream_t stream) {
    const float* x    = (const float*)d_in[0];  // [64,512,256]
    const float* W_w  = (const float*)d_in[1];  // [256,256]
    const float* W_b  = (const float*)d_in[2];  // [256]
    // d_in[3] = att_w, d_in[4] = att_b — provably unused (softmax sums to 1)
    float* out = (float*)d_out;                 // [64,512,256] fp32

    fcgat_gemm<<<(M_TOTAL / 64) * 4, 256, 0, stream>>>(x, W_w, W_b, out);
}

// Round 5
// 90.431 us; speedup vs baseline: 1.2791x; 1.1289x over previous
//
#include <hip/hip_runtime.h>
#include <hip/hip_bf16.h>

// Problem: N=64, K=512, D=256. Reference reduces to out = relu(x @ W^T + b):
// softmax over j sums to 1 and einsum 'nkj,nkd->nkd' multiplies h by that sum.
// [32768,256] x [256,256]^T GEMM + bias + ReLU. Memory-bound (~67 MB HBM).
//
// R1: register-resident B -> AGPR-ized, latency-bound 42us @ 1.2 TB/s.
// R2/R3: LDS W-slice + deep A-prefetch -> ~35us (divergent loads).
// R4: coalesced LDS staging of x+W -> ~29us, but 4x redundant x reads
//     (4 e-blocks per m-tile, served cross-XCD by L3) + phase serialization.
// R5: persistent full-W block. W (256x256 bf16, stride 264) in 132 KB LDS,
//     staged ONCE per CU. 256 blocks x 128 m-rows: x read exactly once,
//     coalesced, with register prefetch of the next 32-row tile issued
//     before the current tile's MFMA. Ideal traffic 67 MB -> ~11 us.

#define DD 256          // feature dim
#define M_TOTAL 32768   // N*K rows
#define LWS 264         // LDS row stride in shorts (528 B): 2-way banks, free

typedef short bf16x8 __attribute__((ext_vector_type(8)));
typedef float floatx16 __attribute__((ext_vector_type(16)));

// Pack 8 fp32 -> 8 bf16 (packed cvt, RNE).
__device__ inline bf16x8 pack8(float4 p0, float4 p1) {
    __hip_bfloat162 q0 = __float22bfloat162_rn(make_float2(p0.x, p0.y));
    __hip_bfloat162 q1 = __float22bfloat162_rn(make_float2(p0.z, p0.w));
    __hip_bfloat162 q2 = __float22bfloat162_rn(make_float2(p1.x, p1.y));
    __hip_bfloat162 q3 = __float22bfloat162_rn(make_float2(p1.z, p1.w));
    union { bf16x8 v; unsigned u[4]; } r;
    union { __hip_bfloat162 h; unsigned u; } c;
    c.h = q0; r.u[0] = c.u;
    c.h = q1; r.u[1] = c.u;
    c.h = q2; r.u[2] = c.u;
    c.h = q3; r.u[3] = c.u;
    return r.v;
}

// 512 thr = 8 waves; wave w owns e-strip [w*32, w*32+32). Block owns 128
// contiguous m-rows = 4 tiles of 32. 1 block/CU (148.5 KB LDS), grid = 256.
__global__ void __launch_bounds__(512, 1)
fcgat_gemm(const float* __restrict__ x, const float* __restrict__ W,
           const float* __restrict__ Wbias, float* __restrict__ out) {
    __shared__ __align__(16) unsigned short lw[256 * LWS];  // 132 KB
    __shared__ __align__(16) unsigned short lx[32 * LWS];   // 16.5 KB

    const int tid   = threadIdx.x;        // 0..511
    const int r0    = tid >> 5;           // 0..15 (staging row base)
    const int c0    = (tid & 31) * 8;     // staging col (floats/shorts)
    const int mbase = blockIdx.x * 128;

    // ---- prefetch x tile 0 FIRST (HBM latency drains during W staging) ----
    float4 xp[4];
    {
        const float* s0 = x + (mbase + r0) * DD + c0;
        const float* s1 = x + (mbase + 16 + r0) * DD + c0;
        xp[0] = *(const float4*)(s0);
        xp[1] = *(const float4*)(s0 + 4);
        xp[2] = *(const float4*)(s1);
        xp[3] = *(const float4*)(s1 + 4);
    }

    // ---- stage full W fp32 -> bf16 -> LDS (coalesced: wave covers 2 rows) --
#pragma unroll
    for (int k = 0; k < 16; ++k) {
        const int r = r0 + 16 * k;        // 0..255
        const float* ws = W + r * DD + c0;
        float4 a0 = *(const float4*)(ws);
        float4 a1 = *(const float4*)(ws + 4);
        *(bf16x8*)(lw + r * LWS + c0) = pack8(a0, a1);
    }

    // ---- write x tile 0 ----
    *(bf16x8*)(lx + r0 * LWS + c0)        = pack8(xp[0], xp[1]);
    *(bf16x8*)(lx + (16 + r0) * LWS + c0) = pack8(xp[2], xp[3]);
    __syncthreads();

    const int lane = tid & 63;
    const int wave = tid >> 6;            // 0..7 -> e-strip
    const int ln   = lane & 31;
    const int lh   = lane >> 5;           // k-half (0/1)

    const unsigned short* ap = lx + ln * LWS + lh * 8;
    const unsigned short* bp = lw + (wave * 32 + ln) * LWS + lh * 8;
    const float bias = Wbias[wave * 32 + ln];
    float* ob = out + wave * 32 + ln;

#pragma unroll
    for (int t = 0; t < 4; ++t) {
        const int m0 = mbase + t * 32;

        // prefetch next tile's x while this tile computes
        if (t < 3) {
            const float* s0 = x + (m0 + 32 + r0) * DD + c0;
            const float* s1 = x + (m0 + 48 + r0) * DD + c0;
            xp[0] = *(const float4*)(s0);
            xp[1] = *(const float4*)(s0 + 4);
            xp[2] = *(const float4*)(s1);
            xp[3] = *(const float4*)(s1 + 4);
        }

        floatx16 acc;
#pragma unroll
        for (int i = 0; i < 16; ++i) acc[i] = 0.f;

#pragma unroll
        for (int s = 0; s < 16; ++s) {
            bf16x8 af = *(const bf16x8*)(ap + s * 16);
            bf16x8 bf = *(const bf16x8*)(bp + s * 16);
            acc = __builtin_amdgcn_mfma_f32_32x32x16_bf16(af, bf, acc, 0, 0, 0);
        }

        // epilogue: bias + relu, nontemporal fp32 store
        // C/D layout: col = lane&31, row = (reg&3) + 8*(reg>>2) + 4*(lane>>5)
#pragma unroll
        for (int r = 0; r < 16; ++r) {
            const int m = m0 + (r & 3) + 8 * (r >> 2) + 4 * lh;
            float v = acc[r] + bias;
            v = v > 0.f ? v : 0.f;
            __builtin_nontemporal_store(v, ob + m * DD);
        }

        __syncthreads();                  // all waves done reading lx
        if (t < 3) {
            *(bf16x8*)(lx + r0 * LWS + c0)        = pack8(xp[0], xp[1]);
            *(bf16x8*)(lx + (16 + r0) * LWS + c0) = pack8(xp[2], xp[3]);
        }
        __syncthreads();                  // lx refilled
    }
}

extern "C" void kernel_launch(void* const* d_in, const int* in_sizes, int n_in,
                              void* d_out, int out_size, void* d_ws, size_t ws_size,
                              hipStream_t stream) {
    const float* x    = (const float*)d_in[0];  // [64,512,256]
    const float* W_w  = (const float*)d_in[1];  // [256,256]
    const float* W_b  = (const float*)d_in[2];  // [256]
    // d_in[3] = att_w, d_in[4] = att_b — provably unused (softmax sums to 1)
    float* out = (float*)d_out;                 // [64,512,256] fp32

    fcgat_gemm<<<M_TOTAL / 128, 512, 0, stream>>>(x, W_w, W_b, out);
}

// Round 6
// 90.231 us; speedup vs baseline: 1.2820x; 1.0022x over previous
//
#include <hip/hip_runtime.h>
#include <hip/hip_bf16.h>

// Problem: N=64, K=512, D=256. Reference reduces to out = relu(x @ W^T + b):
// softmax over j sums to 1 and einsum 'nkj,nkd->nkd' multiplies h by that sum.
// [32768,256] x [256,256]^T GEMM + bias + ReLU. Memory-bound (~67 MB HBM).
//
// R1: register-resident B -> AGPR-ized, latency-bound 42us @ 1.2 TB/s.
// R2/R3: LDS W-slice + deep A-prefetch -> ~35us (divergent loads).
// R4: coalesced LDS staging -> ~29us (4x redundant x reads across e-blocks).
// R5: persistent full-W block, x read once -> ~17us. Residual: __syncthreads
//     emits s_waitcnt vmcnt(0), draining prefetch loads AND nt-stores at
//     every barrier (serializing ~64KB of HBM traffic per tile, MFMA idle).
// R6: lgkm-only barriers (inline asm s_waitcnt lgkmcnt(0); s_barrier) --
//     LDS producer/consumer is CU-local, global stores are never cross-read.
//     2-tile-deep register prefetch + stores moved after the refill barrier:
//     no vmcnt(0) anywhere in the loop, HBM streams continuously.

#define DD 256          // feature dim
#define M_TOTAL 32768   // N*K rows
#define LWS 264         // LDS row stride in shorts (528 B): measured 0 conflicts

typedef short bf16x8 __attribute__((ext_vector_type(8)));
typedef float floatx16 __attribute__((ext_vector_type(16)));

// Barrier with LDS-only drain: does NOT wait vmcnt, so global prefetch
// loads and nontemporal stores stay in flight across it.
#define BAR() asm volatile("s_waitcnt lgkmcnt(0)\n\ts_barrier" ::: "memory")

// Pack 8 fp32 -> 8 bf16 (packed cvt, RNE).
__device__ inline bf16x8 pack8(float4 p0, float4 p1) {
    __hip_bfloat162 q0 = __float22bfloat162_rn(make_float2(p0.x, p0.y));
    __hip_bfloat162 q1 = __float22bfloat162_rn(make_float2(p0.z, p0.w));
    __hip_bfloat162 q2 = __float22bfloat162_rn(make_float2(p1.x, p1.y));
    __hip_bfloat162 q3 = __float22bfloat162_rn(make_float2(p1.z, p1.w));
    union { bf16x8 v; unsigned u[4]; } r;
    union { __hip_bfloat162 h; unsigned u; } c;
    c.h = q0; r.u[0] = c.u;
    c.h = q1; r.u[1] = c.u;
    c.h = q2; r.u[2] = c.u;
    c.h = q3; r.u[3] = c.u;
    return r.v;
}

// Each thread's share of one 32-row x tile: rows r0 and r0+16, 8 floats at c0.
__device__ inline void load_tile(const float* __restrict__ x, int m0,
                                 int r0, int c0, float4 P[4]) {
    const float* s0 = x + (m0 + r0) * DD + c0;
    const float* s1 = x + (m0 + 16 + r0) * DD + c0;
    P[0] = *(const float4*)(s0);
    P[1] = *(const float4*)(s0 + 4);
    P[2] = *(const float4*)(s1);
    P[3] = *(const float4*)(s1 + 4);
}

__device__ inline void write_lx(unsigned short* lx, int r0, int c0,
                                const float4 P[4]) {
    *(bf16x8*)(lx + r0 * LWS + c0)        = pack8(P[0], P[1]);
    *(bf16x8*)(lx + (16 + r0) * LWS + c0) = pack8(P[2], P[3]);
}

__device__ inline void compute_tile(const unsigned short* ap,
                                    const unsigned short* bp, floatx16& acc) {
#pragma unroll
    for (int i = 0; i < 16; ++i) acc[i] = 0.f;
#pragma unroll
    for (int s = 0; s < 16; ++s) {
        bf16x8 af = *(const bf16x8*)(ap + s * 16);
        bf16x8 bf = *(const bf16x8*)(bp + s * 16);
        acc = __builtin_amdgcn_mfma_f32_32x32x16_bf16(af, bf, acc, 0, 0, 0);
    }
}

// C/D layout: col = lane&31, row = (reg&3) + 8*(reg>>2) + 4*(lane>>5)
__device__ inline void store_tile(float* ob, int m0, int lh, float bias,
                                  const floatx16& acc) {
#pragma unroll
    for (int r = 0; r < 16; ++r) {
        const int m = m0 + (r & 3) + 8 * (r >> 2) + 4 * lh;
        float v = acc[r] + bias;
        v = v > 0.f ? v : 0.f;
        __builtin_nontemporal_store(v, ob + m * DD);
    }
}

// 512 thr = 8 waves; wave w owns e-strip [w*32, w*32+32). Block owns 128
// contiguous m-rows = 4 tiles of 32. 1 block/CU (148.5 KB LDS), grid = 256.
__global__ void __launch_bounds__(512, 1)
fcgat_gemm(const float* __restrict__ x, const float* __restrict__ W,
           const float* __restrict__ Wbias, float* __restrict__ out) {
    __shared__ __align__(16) unsigned short lw[256 * LWS];  // 132 KB
    __shared__ __align__(16) unsigned short lx[32 * LWS];   // 16.5 KB

    const int tid   = threadIdx.x;        // 0..511
    const int r0    = tid >> 5;           // 0..15 (staging row base)
    const int c0    = (tid & 31) * 8;     // staging col (floats/shorts)
    const int mbase = blockIdx.x * 128;

    // ---- issue tile0 + tile1 prefetch FIRST (in flight during W staging) --
    float4 Pa[4], Pb[4];
    load_tile(x, mbase + 0,  r0, c0, Pa);
    load_tile(x, mbase + 32, r0, c0, Pb);

    // ---- stage full W fp32 -> bf16 -> LDS (coalesced: 32 lanes = 1 row) ---
#pragma unroll
    for (int k = 0; k < 16; ++k) {
        const int r = r0 + 16 * k;        // 0..255
        const float* ws = W + r * DD + c0;
        float4 a0 = *(const float4*)(ws);
        float4 a1 = *(const float4*)(ws + 4);
        *(bf16x8*)(lw + r * LWS + c0) = pack8(a0, a1);
    }

    write_lx(lx, r0, c0, Pa);             // waits only Pa's loads (fine vmcnt)
    BAR();

    const int lane = tid & 63;
    const int wave = tid >> 6;            // 0..7 -> e-strip
    const int ln   = lane & 31;
    const int lh   = lane >> 5;           // k-half (0/1)

    const unsigned short* ap = lx + ln * LWS + lh * 8;
    const unsigned short* bp = lw + (wave * 32 + ln) * LWS + lh * 8;
    const float bias = Wbias[wave * 32 + ln];
    float* ob = out + wave * 32 + ln;

    floatx16 acc;

    // ---- tile 0 ----
    compute_tile(ap, bp, acc);
    BAR();                                // lx free
    write_lx(lx, r0, c0, Pb);             // tile1 (loaded ~2.7us ago)
    load_tile(x, mbase + 64, r0, c0, Pa); // tile2 into free slot
    BAR();                                // lx ready
    store_tile(ob, mbase + 0, lh, bias, acc);   // drains during tile1 compute

    // ---- tile 1 ----
    compute_tile(ap, bp, acc);
    BAR();
    write_lx(lx, r0, c0, Pa);             // tile2
    load_tile(x, mbase + 96, r0, c0, Pb); // tile3
    BAR();
    store_tile(ob, mbase + 32, lh, bias, acc);

    // ---- tile 2 ----
    compute_tile(ap, bp, acc);
    BAR();
    write_lx(lx, r0, c0, Pb);             // tile3
    BAR();
    store_tile(ob, mbase + 64, lh, bias, acc);

    // ---- tile 3 ----
    compute_tile(ap, bp, acc);
    store_tile(ob, mbase + 96, lh, bias, acc);
}

extern "C" void kernel_launch(void* const* d_in, const int* in_sizes, int n_in,
                              void* d_out, int out_size, void* d_ws, size_t ws_size,
                              hipStream_t stream) {
    const float* x    = (const float*)d_in[0];  // [64,512,256]
    const float* W_w  = (const float*)d_in[1];  // [256,256]
    const float* W_b  = (const float*)d_in[2];  // [256]
    // d_in[3] = att_w, d_in[4] = att_b — provably unused (softmax sums to 1)
    float* out = (float*)d_out;                 // [64,512,256] fp32

    fcgat_gemm<<<M_TOTAL / 128, 512, 0, stream>>>(x, W_w, W_b, out);
}